// Round 3
// baseline (8231.870 us; speedup 1.0000x reference)
//
#include <hip/hip_runtime.h>
#include <hip/hip_bf16.h>
#include <math.h>

// Problem constants
#define D_MODEL 2048
#define D_STATE 16
#define D_CONV  4
#define DT_RANK 128
#define D_INNER 4096
#define BATCH   4
#define SEQLEN  2048
#define BL      (BATCH * SEQLEN)   // 8192 tokens

typedef __hip_bfloat16 bf16;

__device__ __forceinline__ float bf2f(bf16 v) { return __bfloat162float(v); }
__device__ __forceinline__ bf16  f2bf(float v) { return __float2bfloat16(v); }

// load 4 consecutive elements as float4 (fp32 or bf16 source)
__device__ __forceinline__ float4 ld4(const float* p) { return *(const float4*)p; }
__device__ __forceinline__ float4 ld4(const bf16* p) {
    ushort4 u = *(const ushort4*)p;
    float4 f;
    f.x = __uint_as_float((unsigned)u.x << 16);
    f.y = __uint_as_float((unsigned)u.y << 16);
    f.z = __uint_as_float((unsigned)u.z << 16);
    f.w = __uint_as_float((unsigned)u.w << 16);
    return f;
}
__device__ __forceinline__ void st1(float* p, float v) { *p = v; }
__device__ __forceinline__ void st1(bf16* p, float v)  { *p = f2bf(v); }

// ---------------------------------------------------------------------------
// NT GEMM: C[M,N] = sum_k A[m,k] * B[n,k].  fp32 accumulate; A/B/C dtypes
// templated (bf16 converted at load/store).  128x128 tile, BK=16, 256 thr,
// 8x8 micro-tile per thread.
// ---------------------------------------------------------------------------
#define BM 128
#define BN 128
#define BK 16

template <typename TA, typename TB, typename TC>
__global__ __launch_bounds__(256) void gemm_nt(
    const TA* __restrict__ A, const TB* __restrict__ B,
    TC* __restrict__ C, int M, int N, int K, int lda, int ldb, int ldc)
{
    __shared__ float As[BK][BM + 4];
    __shared__ float Bs[BK][BN + 4];

    const int tid = threadIdx.x;
    const int tx  = tid & 15;        // 0..15 -> N direction
    const int ty  = tid >> 4;        // 0..15 -> M direction
    const int m0  = blockIdx.x * BM;
    const int n0  = blockIdx.y * BN;

    const int r  = tid >> 2;         // 0..63 (load row)
    const int c4 = (tid & 3) * 4;    // 0,4,8,12 (load col group)

    float acc[8][8];
#pragma unroll
    for (int i = 0; i < 8; ++i)
#pragma unroll
        for (int j = 0; j < 8; ++j) acc[i][j] = 0.f;

    for (int k0 = 0; k0 < K; k0 += BK) {
#pragma unroll
        for (int half = 0; half < 2; ++half) {
            int rr = r + half * 64;
            float4 v = make_float4(0.f, 0.f, 0.f, 0.f);
            if (m0 + rr < M)
                v = ld4(A + (size_t)(m0 + rr) * lda + k0 + c4);
            As[c4 + 0][rr] = v.x; As[c4 + 1][rr] = v.y;
            As[c4 + 2][rr] = v.z; As[c4 + 3][rr] = v.w;

            float4 w = make_float4(0.f, 0.f, 0.f, 0.f);
            if (n0 + rr < N)
                w = ld4(B + (size_t)(n0 + rr) * ldb + k0 + c4);
            Bs[c4 + 0][rr] = w.x; Bs[c4 + 1][rr] = w.y;
            Bs[c4 + 2][rr] = w.z; Bs[c4 + 3][rr] = w.w;
        }
        __syncthreads();

#pragma unroll
        for (int kk = 0; kk < BK; ++kk) {
            float a[8], b[8];
            *(float4*)&a[0] = *(const float4*)&As[kk][ty * 8];
            *(float4*)&a[4] = *(const float4*)&As[kk][ty * 8 + 4];
            *(float4*)&b[0] = *(const float4*)&Bs[kk][tx * 8];
            *(float4*)&b[4] = *(const float4*)&Bs[kk][tx * 8 + 4];
#pragma unroll
            for (int i = 0; i < 8; ++i)
#pragma unroll
                for (int j = 0; j < 8; ++j)
                    acc[i][j] = fmaf(a[i], b[j], acc[i][j]);
        }
        __syncthreads();
    }

#pragma unroll
    for (int i = 0; i < 8; ++i) {
        int m = m0 + ty * 8 + i;
        if (m >= M) continue;
#pragma unroll
        for (int j = 0; j < 8; ++j) {
            int n = n0 + tx * 8 + j;
            if (n < N) st1(C + (size_t)m * ldc + n, acc[i][j]);
        }
    }
}

// ---------------------------------------------------------------------------
// Depthwise causal conv1d (width 4) + bias + SiLU.  bf16 in/out, fp32 math.
// ---------------------------------------------------------------------------
__global__ void conv_silu(const bf16* __restrict__ X,
                          const float* __restrict__ conv_w,
                          const float* __restrict__ conv_b,
                          bf16* __restrict__ xact)
{
    unsigned idx = blockIdx.x * blockDim.x + threadIdx.x;  // over BL*4096
    if (idx >= (unsigned)BL * D_INNER) return;
    int c = idx & (D_INNER - 1);
    unsigned bl = idx >> 12;           // / 4096
    int l = bl & (SEQLEN - 1);
    int b = bl >> 11;                  // / 2048

    float acc = conv_b[c];
#pragma unroll
    for (int t = 0; t < D_CONV; ++t) {
        int ll = l - (D_CONV - 1) + t;
        if (ll >= 0)
            acc = fmaf(bf2f(X[((size_t)b * SEQLEN + ll) * D_INNER + c]),
                       conv_w[c * D_CONV + t], acc);
    }
    float s = acc / (1.f + __expf(-acc));     // SiLU
    xact[(size_t)bl * D_INNER + c] = f2bf(s);
}

// ---------------------------------------------------------------------------
// Selective scan. One thread per (b, d). Block = 64 threads (one wave),
// grid = (64 channel-groups, BATCH). B/C staged in LDS per 64-step chunk.
// Fuses softplus(dt+bias), scan, +D*u skip, *silu(z) gating.  y aliases xact.
// ---------------------------------------------------------------------------
__global__ __launch_bounds__(64) void scan_kernel(
    const bf16* __restrict__ xact, const bf16* __restrict__ dtraw,
    const float* __restrict__ xdbl, const float* __restrict__ dt_bias,
    const float* __restrict__ A_log, const float* __restrict__ Dp,
    const bf16* __restrict__ Z, bf16* __restrict__ ybuf)
{
    const int b = blockIdx.y;
    const int d = blockIdx.x * 64 + threadIdx.x;

    float A[D_STATE];
#pragma unroll
    for (int n = 0; n < D_STATE; ++n)
        A[n] = -__expf(A_log[(size_t)d * D_STATE + n]);

    const float bias = dt_bias[d];
    const float Dv   = Dp[d];

    float h[D_STATE];
#pragma unroll
    for (int n = 0; n < D_STATE; ++n) h[n] = 0.f;

    __shared__ float BC[64][2 * D_STATE];   // [l-chunk][B(16) then C(16)]

    const float* xd = xdbl + (size_t)b * SEQLEN * (DT_RANK + 2 * D_STATE);

    for (int l0 = 0; l0 < SEQLEN; l0 += 64) {
        __syncthreads();
        {
            const float* src = xd + (size_t)(l0 + threadIdx.x) * (DT_RANK + 2 * D_STATE) + DT_RANK;
            float4* dst = (float4*)BC[threadIdx.x];
#pragma unroll
            for (int q = 0; q < 8; ++q) dst[q] = ((const float4*)src)[q];
        }
        __syncthreads();

        for (int l = l0; l < l0 + 64; ++l) {
            size_t bl = (size_t)b * SEQLEN + l;
            float u   = bf2f(xact[bl * D_INNER + d]);
            float dtv = bf2f(dtraw[bl * D_INNER + d]) + bias;
            float delta = (dtv > 20.f) ? dtv : log1pf(__expf(dtv));
            float du = delta * u;
            const float* Bc = BC[l - l0];
            float y = 0.f;
#pragma unroll
            for (int n = 0; n < D_STATE; ++n) {
                float dA = __expf(delta * A[n]);
                h[n] = fmaf(h[n], dA, du * Bc[n]);
                y = fmaf(h[n], Bc[D_STATE + n], y);
            }
            float z = bf2f(Z[bl * D_INNER + d]);
            float g = z / (1.f + __expf(-z));       // silu(z)
            ybuf[bl * D_INNER + d] = f2bf((y + Dv * u) * g);
        }
    }
}

// ---------------------------------------------------------------------------
// Launch.  Workspace (bytes):
//   X    : BL*D_INNER bf16 = 64 MiB   (dead after conv -> reused as dtraw)
//   xact : BL*D_INNER bf16 = 64 MiB   (scan writes y in place)
//   xdbl : BL*160 fp32     =  5 MiB
//   Z    : bf16, parked INSIDE d_out (67.1 MB, exactly fits; dead before
//          out_proj overwrites d_out)
// need = 139,460,608 B.  If ws_size < need: zero d_out and bail (clean,
// diagnostic failure instead of a GPU memory fault).
// ---------------------------------------------------------------------------
extern "C" void kernel_launch(void* const* d_in, const int* in_sizes, int n_in,
                              void* d_out, int out_size, void* d_ws, size_t ws_size,
                              hipStream_t stream)
{
    const float* hs      = (const float*)d_in[0];
    const float* W_in    = (const float*)d_in[1];
    const float* conv_w  = (const float*)d_in[2];
    const float* conv_b  = (const float*)d_in[3];
    const float* W_x     = (const float*)d_in[4];
    const float* W_dt    = (const float*)d_in[5];
    const float* dt_bias = (const float*)d_in[6];
    const float* A_log   = (const float*)d_in[7];
    const float* Dp      = (const float*)d_in[8];
    const float* W_out   = (const float*)d_in[9];
    float* out = (float*)d_out;

    const size_t nBig = (size_t)BL * D_INNER;            // 33,554,432
    const size_t need = 2 * nBig * sizeof(bf16)          // X + xact
                      + (size_t)BL * 160 * sizeof(float); // xdbl
    if (ws_size < need) {
        hipMemsetAsync(d_out, 0, (size_t)out_size * sizeof(float), stream);
        return;  // clean diagnostic failure: ws too small for this plan
    }

    bf16*  X     = (bf16*)d_ws;                 // 64 MiB
    bf16*  xact  = X + nBig;                    // 64 MiB
    float* xdbl  = (float*)(xact + nBig);       // 5 MiB
    bf16*  dtraw = X;                           // alias (X dead after conv)
    bf16*  Z     = (bf16*)d_out;                // parked in d_out

    // 1a) in_proj x-half: X = hs @ W_in[0:4096]^T   (M=8192, N=4096, K=2048)
    gemm_nt<<<dim3(BL / BM, D_INNER / BN), 256, 0, stream>>>(
        hs, W_in, X, BL, D_INNER, D_MODEL, D_MODEL, D_MODEL, D_INNER);

    // 1b) in_proj z-half: Z = hs @ W_in[4096:8192]^T  (-> d_out as bf16)
    gemm_nt<<<dim3(BL / BM, D_INNER / BN), 256, 0, stream>>>(
        hs, W_in + (size_t)D_INNER * D_MODEL, Z, BL, D_INNER, D_MODEL,
        D_MODEL, D_MODEL, D_INNER);

    // 2) causal depthwise conv + SiLU -> xact
    conv_silu<<<(BL * D_INNER + 255) / 256, 256, 0, stream>>>(X, conv_w, conv_b, xact);

    // 3) x_proj: xdbl = xact @ W_x^T   (M=8192, N=160, K=4096)
    gemm_nt<<<dim3(BL / BM, (DT_RANK + 2 * D_STATE + BN - 1) / BN), 256, 0, stream>>>(
        xact, W_x, xdbl, BL, DT_RANK + 2 * D_STATE, D_INNER,
        D_INNER, D_INNER, DT_RANK + 2 * D_STATE);

    // 4) dt proj: dtraw = xdbl[:, :128] @ W_dt^T   (M=8192, N=4096, K=128)
    gemm_nt<<<dim3(BL / BM, D_INNER / BN), 256, 0, stream>>>(
        xdbl, W_dt, dtraw, BL, D_INNER, DT_RANK,
        DT_RANK + 2 * D_STATE, DT_RANK, D_INNER);

    // 5) selective scan. y aliases xact; consumes Z (frees d_out).
    scan_kernel<<<dim3(D_INNER / 64, BATCH), 64, 0, stream>>>(
        xact, dtraw, xdbl, dt_bias, A_log, Dp, Z, xact);

    // 6) out_proj: out = y @ W_out^T   (M=8192, N=2048, K=4096)
    gemm_nt<<<dim3(BL / BM, D_MODEL / BN), 256, 0, stream>>>(
        xact, W_out, out, BL, D_MODEL, D_INNER, D_INNER, D_INNER, D_MODEL);
}

// Round 4
// 4441.231 us; speedup vs baseline: 1.8535x; 1.8535x over previous
//
#include <hip/hip_runtime.h>
#include <hip/hip_bf16.h>
#include <math.h>

// Problem constants
#define D_MODEL 2048
#define D_STATE 16
#define D_CONV  4
#define DT_RANK 128
#define D_INNER 4096
#define BATCH   4
#define SEQLEN  2048
#define BL      (BATCH * SEQLEN)   // 8192 tokens

typedef __hip_bfloat16 bf16;
typedef __attribute__((ext_vector_type(8))) short  short8;   // 8 bf16 (4 VGPRs)
typedef __attribute__((ext_vector_type(4))) float  f32x4;

__device__ __forceinline__ float bf2f(bf16 v) { return __bfloat162float(v); }
__device__ __forceinline__ bf16  f2bf(float v) { return __float2bfloat16(v); }

__device__ __forceinline__ float4 ld4(const float* p) { return *(const float4*)p; }
__device__ __forceinline__ float4 ld4(const bf16* p) {
    ushort4 u = *(const ushort4*)p;
    float4 f;
    f.x = __uint_as_float((unsigned)u.x << 16);
    f.y = __uint_as_float((unsigned)u.y << 16);
    f.z = __uint_as_float((unsigned)u.z << 16);
    f.w = __uint_as_float((unsigned)u.w << 16);
    return f;
}
__device__ __forceinline__ void st1(float* p, float v) { *p = v; }
__device__ __forceinline__ void st1(bf16* p, float v)  { *p = f2bf(v); }

// ---------------------------------------------------------------------------
// bf16 MFMA NT GEMM: C[M,N] = sum_k A[m,k]*B[n,k]; A (M,K) bf16, B (N,K) bf16.
// 128x128 tile, BK=64, 256 threads (4 waves, 2x2), 4x4 16x16x32 frags/wave.
// global_load_lds width=16 staging (m97 recipe). M,N,K must divide 128/128/64.
// ---------------------------------------------------------------------------
__device__ __forceinline__ void async_cp16(const bf16* g, bf16* l) {
    __builtin_amdgcn_global_load_lds(
        (const __attribute__((address_space(1))) void*)g,
        (__attribute__((address_space(3))) void*)l, 16, 0, 0);
}

template <typename TC>
__global__ __launch_bounds__(256) void gemm_mfma_nt(
    const bf16* __restrict__ A, const bf16* __restrict__ B,
    TC* __restrict__ C, int M, int N, int K)
{
    __shared__ bf16 As[128][64];   // 16 KB
    __shared__ bf16 Bs[128][64];   // 16 KB

    const int tid  = threadIdx.x;
    const int lane = tid & 63;
    const int wave = tid >> 6;          // 0..3
    const int wm   = (wave >> 1) * 64;
    const int wn   = (wave & 1) * 64;

    const int m0 = blockIdx.x * 128;
    const int n0 = blockIdx.y * 128;

    f32x4 acc[4][4] = {};

    // staging geometry: one inst = 64 lanes x 16 B = 8 rows x (64 bf16 = 128 B)
    const int srow = lane >> 3;          // 0..7 within segment
    const int scol = (lane & 7) * 8;     // element offset within row

    for (int k0 = 0; k0 < K; k0 += 64) {
        __syncthreads();   // previous iter's ds_reads done before overwrite
#pragma unroll
        for (int i = 0; i < 4; ++i) {
            int seg = wave * 4 + i;               // 0..15 -> rows seg*8..+7
            int row = seg * 8 + srow;
            async_cp16(A + (size_t)(m0 + row) * K + k0 + scol, &As[seg * 8][0]);
            async_cp16(B + (size_t)(n0 + row) * K + k0 + scol, &Bs[seg * 8][0]);
        }
        __syncthreads();   // vmcnt(0) drained by barrier semantics

#pragma unroll
        for (int kk = 0; kk < 64; kk += 32) {
            short8 a[4], b[4];
            const int fr = lane & 15;
            const int fk = kk + (lane >> 4) * 8;
#pragma unroll
            for (int i = 0; i < 4; ++i) {
                a[i] = *(const short8*)&As[wm + i * 16 + fr][fk];
                b[i] = *(const short8*)&Bs[wn + i * 16 + fr][fk];
            }
#pragma unroll
            for (int i = 0; i < 4; ++i)
#pragma unroll
                for (int j = 0; j < 4; ++j)
                    acc[i][j] = __builtin_amdgcn_mfma_f32_16x16x32_bf16(
                        a[i], b[j], acc[i][j], 0, 0, 0);
        }
    }

    // C/D layout: col = lane&15, row = (lane>>4)*4 + reg   [m89-verified]
#pragma unroll
    for (int i = 0; i < 4; ++i) {
        int row = m0 + wm + i * 16 + (lane >> 4) * 4;
#pragma unroll
        for (int j = 0; j < 4; ++j) {
            int col = n0 + wn + j * 16 + (lane & 15);
#pragma unroll
            for (int r = 0; r < 4; ++r)
                st1(C + (size_t)(row + r) * N + col, acc[i][j][r]);
        }
    }
}

// ---------------------------------------------------------------------------
// fp32-accumulate vector GEMM (templated dtypes) for the skinny projections.
// ---------------------------------------------------------------------------
#define BM 128
#define BN 128
#define BK 16

template <typename TA, typename TB, typename TC>
__global__ __launch_bounds__(256) void gemm_nt(
    const TA* __restrict__ A, const TB* __restrict__ B,
    TC* __restrict__ C, int M, int N, int K, int lda, int ldb, int ldc)
{
    __shared__ float As[BK][BM + 4];
    __shared__ float Bs[BK][BN + 4];

    const int tid = threadIdx.x;
    const int tx  = tid & 15;
    const int ty  = tid >> 4;
    const int m0  = blockIdx.x * BM;
    const int n0  = blockIdx.y * BN;

    const int r  = tid >> 2;
    const int c4 = (tid & 3) * 4;

    float acc[8][8];
#pragma unroll
    for (int i = 0; i < 8; ++i)
#pragma unroll
        for (int j = 0; j < 8; ++j) acc[i][j] = 0.f;

    for (int k0 = 0; k0 < K; k0 += BK) {
#pragma unroll
        for (int half = 0; half < 2; ++half) {
            int rr = r + half * 64;
            float4 v = make_float4(0.f, 0.f, 0.f, 0.f);
            if (m0 + rr < M) v = ld4(A + (size_t)(m0 + rr) * lda + k0 + c4);
            As[c4 + 0][rr] = v.x; As[c4 + 1][rr] = v.y;
            As[c4 + 2][rr] = v.z; As[c4 + 3][rr] = v.w;

            float4 w = make_float4(0.f, 0.f, 0.f, 0.f);
            if (n0 + rr < N) w = ld4(B + (size_t)(n0 + rr) * ldb + k0 + c4);
            Bs[c4 + 0][rr] = w.x; Bs[c4 + 1][rr] = w.y;
            Bs[c4 + 2][rr] = w.z; Bs[c4 + 3][rr] = w.w;
        }
        __syncthreads();

#pragma unroll
        for (int kk = 0; kk < BK; ++kk) {
            float a[8], b[8];
            *(float4*)&a[0] = *(const float4*)&As[kk][ty * 8];
            *(float4*)&a[4] = *(const float4*)&As[kk][ty * 8 + 4];
            *(float4*)&b[0] = *(const float4*)&Bs[kk][tx * 8];
            *(float4*)&b[4] = *(const float4*)&Bs[kk][tx * 8 + 4];
#pragma unroll
            for (int i = 0; i < 8; ++i)
#pragma unroll
                for (int j = 0; j < 8; ++j)
                    acc[i][j] = fmaf(a[i], b[j], acc[i][j]);
        }
        __syncthreads();
    }

#pragma unroll
    for (int i = 0; i < 8; ++i) {
        int m = m0 + ty * 8 + i;
        if (m >= M) continue;
#pragma unroll
        for (int j = 0; j < 8; ++j) {
            int n = n0 + tx * 8 + j;
            if (n < N) st1(C + (size_t)m * ldc + n, acc[i][j]);
        }
    }
}

// ---------------------------------------------------------------------------
// fp32 -> bf16 conversion (4 elems/thread); n must be a multiple of 4.
// ---------------------------------------------------------------------------
__global__ void cvt_f32_bf16(const float* __restrict__ src,
                             bf16* __restrict__ dst, int n)
{
    int i = (blockIdx.x * blockDim.x + threadIdx.x) * 4;
    if (i >= n) return;
    float4 v = *(const float4*)(src + i);
    bf16 o[4] = { f2bf(v.x), f2bf(v.y), f2bf(v.z), f2bf(v.w) };
    *(ushort4*)(dst + i) = *(ushort4*)o;
}

// ---------------------------------------------------------------------------
// Depthwise causal conv1d (width 4) + bias + SiLU.  bf16 in/out, fp32 math.
// ---------------------------------------------------------------------------
__global__ void conv_silu(const bf16* __restrict__ X,
                          const float* __restrict__ conv_w,
                          const float* __restrict__ conv_b,
                          bf16* __restrict__ xact)
{
    unsigned idx = blockIdx.x * blockDim.x + threadIdx.x;
    if (idx >= (unsigned)BL * D_INNER) return;
    int c = idx & (D_INNER - 1);
    unsigned bl = idx >> 12;
    int l = bl & (SEQLEN - 1);
    int b = bl >> 11;

    float acc = conv_b[c];
#pragma unroll
    for (int t = 0; t < D_CONV; ++t) {
        int ll = l - (D_CONV - 1) + t;
        if (ll >= 0)
            acc = fmaf(bf2f(X[((size_t)b * SEQLEN + ll) * D_INNER + c]),
                       conv_w[c * D_CONV + t], acc);
    }
    float s = acc / (1.f + __expf(-acc));
    xact[(size_t)bl * D_INNER + c] = f2bf(s);
}

// ---------------------------------------------------------------------------
// State-parallel selective scan: 16 lanes per (b,d) channel, one per state n.
// Block 256 = 4 waves = 16 channels; grid (D_INNER/16, BATCH) -> 4096 waves
// (16 waves/CU vs 1 before).  y-reduction: shfl_xor butterfly within 16 lanes.
// Fuses softplus(dt+bias), scan, +D*u skip, *silu(z) gating.
// ybuf may alias Z (same-index read-before-write within the sub==0 lane).
// ---------------------------------------------------------------------------
__global__ __launch_bounds__(256) void scan_kernel(
    const bf16* __restrict__ xact, const bf16* __restrict__ dtraw,
    const float* __restrict__ xdbl, const float* __restrict__ dt_bias,
    const float* __restrict__ A_log, const float* __restrict__ Dp,
    const bf16* __restrict__ Z, bf16* __restrict__ ybuf)
{
    const int b    = blockIdx.y;
    const int lane = threadIdx.x & 63;
    const int wave = threadIdx.x >> 6;
    const int sub  = lane & 15;          // state index n
    const int grp  = lane >> 4;          // channel within wave
    const int d    = blockIdx.x * 16 + wave * 4 + grp;

    const float Av   = -__expf(A_log[(size_t)d * D_STATE + sub]);
    const float bias = dt_bias[d];
    const float Dv   = Dp[d];

    float h = 0.f;
    const size_t base = (size_t)b * SEQLEN;
    const float* xd = xdbl + base * (DT_RANK + 2 * D_STATE) + DT_RANK;

    for (int l = 0; l < SEQLEN; ++l) {
        size_t bl = base + l;
        float u   = bf2f(xact[bl * D_INNER + d]);          // broadcast in group
        float dtv = bf2f(dtraw[bl * D_INNER + d]) + bias;
        float delta = (dtv > 20.f) ? dtv : log1pf(__expf(dtv));
        float Bc = xd[(size_t)l * (DT_RANK + 2 * D_STATE) + sub];
        float Cc = xd[(size_t)l * (DT_RANK + 2 * D_STATE) + D_STATE + sub];
        h = fmaf(h, __expf(delta * Av), delta * u * Bc);
        float p = h * Cc;
        p += __shfl_xor(p, 1, 16);
        p += __shfl_xor(p, 2, 16);
        p += __shfl_xor(p, 4, 16);
        p += __shfl_xor(p, 8, 16);
        if (sub == 0) {
            float z = bf2f(Z[bl * D_INNER + d]);
            float g = z / (1.f + __expf(-z));
            ybuf[bl * D_INNER + d] = f2bf((p + Dv * u) * g);
        }
    }
}

// ---------------------------------------------------------------------------
// Launch.  Workspace = 139,460,608 B (known good from R3):
//   buf1 (64 MiB bf16): X -> dtraw -> W_out_bf16
//   buf2 (64 MiB bf16): Z -> y (in-place alias in scan)
//   xdbl ( 5 MiB fp32)
// d_out doubles as scratch: hs_bf16+W_in_bf16 (50 MB) during in_proj,
// then xact (exactly 67,108,864 B) until out_proj overwrites it with the
// final fp32 result.  Liveness audited per step below.
// ---------------------------------------------------------------------------
extern "C" void kernel_launch(void* const* d_in, const int* in_sizes, int n_in,
                              void* d_out, int out_size, void* d_ws, size_t ws_size,
                              hipStream_t stream)
{
    const float* hs      = (const float*)d_in[0];
    const float* W_in    = (const float*)d_in[1];
    const float* conv_w  = (const float*)d_in[2];
    const float* conv_b  = (const float*)d_in[3];
    const float* W_x     = (const float*)d_in[4];
    const float* W_dt    = (const float*)d_in[5];
    const float* dt_bias = (const float*)d_in[6];
    const float* A_log   = (const float*)d_in[7];
    const float* Dp      = (const float*)d_in[8];
    const float* W_out   = (const float*)d_in[9];
    float* out = (float*)d_out;

    const size_t nBig = (size_t)BL * D_INNER;            // 33,554,432
    const size_t need = 2 * nBig * sizeof(bf16)
                      + (size_t)BL * 160 * sizeof(float);
    if (ws_size < need) {
        hipMemsetAsync(d_out, 0, (size_t)out_size * sizeof(float), stream);
        return;
    }

    bf16*  buf1 = (bf16*)d_ws;              // 64 MiB
    bf16*  buf2 = buf1 + nBig;              // 64 MiB
    float* xdbl = (float*)(buf2 + nBig);    // 5 MiB

    const int nHS = BL * D_MODEL;           // 16,777,216
    const int nWH = D_INNER * D_MODEL;      // 8,388,608 (half of W_in)
    bf16* hsb = (bf16*)d_out;               // [0, nHS)
    bf16* wb  = hsb + nHS;                  // [nHS, nHS+nWH)
    bf16* xact = (bf16*)d_out;              // later phase (hsb/wb dead)

    // --- Phase 1: in_proj (bf16 MFMA) ------------------------------------
    cvt_f32_bf16<<<nHS / 1024, 256, 0, stream>>>(hs, hsb, nHS);
    // z-half first: Z = hsb @ W_in[4096:]^T -> buf2
    cvt_f32_bf16<<<nWH / 1024, 256, 0, stream>>>(W_in + (size_t)nWH, wb, nWH);
    gemm_mfma_nt<<<dim3(BL / 128, D_INNER / 128), 256, 0, stream>>>(
        hsb, wb, buf2, BL, D_INNER, D_MODEL);
    // x-half: X = hsb @ W_in[:4096]^T -> buf1
    cvt_f32_bf16<<<nWH / 1024, 256, 0, stream>>>(W_in, wb, nWH);
    gemm_mfma_nt<<<dim3(BL / 128, D_INNER / 128), 256, 0, stream>>>(
        hsb, wb, buf1, BL, D_INNER, D_MODEL);

    // --- Phase 2: conv + SiLU -> xact (overwrites hsb/wb, now dead) ------
    conv_silu<<<(BL * D_INNER + 255) / 256, 256, 0, stream>>>(
        buf1, conv_w, conv_b, xact);

    // --- Phase 3: x_proj (N=160, fp32 path) -> xdbl ----------------------
    gemm_nt<<<dim3(BL / BM, (DT_RANK + 2 * D_STATE + BN - 1) / BN), 256, 0, stream>>>(
        xact, W_x, xdbl, BL, DT_RANK + 2 * D_STATE, D_INNER,
        D_INNER, D_INNER, DT_RANK + 2 * D_STATE);

    // --- Phase 4: dt_proj (K=128, fp32 path) -> dtraw (buf1; X dead) -----
    gemm_nt<<<dim3(BL / BM, D_INNER / BN), 256, 0, stream>>>(
        xdbl, W_dt, buf1, BL, D_INNER, DT_RANK,
        DT_RANK + 2 * D_STATE, DT_RANK, D_INNER);

    // --- Phase 5: scan.  reads xact,dtraw,Z,xdbl; writes y -> buf2 -------
    scan_kernel<<<dim3(D_INNER / 16, BATCH), 256, 0, stream>>>(
        xact, buf1, xdbl, dt_bias, A_log, Dp, buf2, buf2);

    // --- Phase 6: out_proj (bf16 MFMA).  W_out -> buf1 (dtraw dead) ------
    cvt_f32_bf16<<<nWH / 1024, 256, 0, stream>>>(W_out, buf1, nWH);
    gemm_mfma_nt<<<dim3(BL / 128, D_MODEL / 128), 256, 0, stream>>>(
        buf2, buf1, out, BL, D_MODEL, D_INNER);
}

// Round 5
// 2167.830 us; speedup vs baseline: 3.7973x; 2.0487x over previous
//
#include <hip/hip_runtime.h>
#include <hip/hip_bf16.h>
#include <math.h>

// Problem constants
#define D_MODEL 2048
#define D_STATE 16
#define D_CONV  4
#define DT_RANK 128
#define D_INNER 4096
#define BATCH   4
#define SEQLEN  2048
#define BL      (BATCH * SEQLEN)   // 8192 tokens

typedef __hip_bfloat16 bf16;
typedef __attribute__((ext_vector_type(8))) short  short8;   // 8 bf16 (4 VGPRs)
typedef __attribute__((ext_vector_type(4))) float  f32x4;

__device__ __forceinline__ float bf2f(bf16 v) { return __bfloat162float(v); }
__device__ __forceinline__ bf16  f2bf(float v) { return __float2bfloat16(v); }
__device__ __forceinline__ void st1(float* p, float v) { *p = v; }
__device__ __forceinline__ void st1(bf16* p, float v)  { *p = f2bf(v); }
__device__ __forceinline__ float fast_rcp(float x) { return __builtin_amdgcn_rcpf(x); }

// ---------------------------------------------------------------------------
// bf16 MFMA NT GEMM: C[M,N] = sum_k A[m,k]*B[n,k].
// 128x128 tile, BK=64, 256 threads (4 waves 2x2), 4x4 16x16x32 frags/wave.
// global_load_lds width=16 staging.  M%128==0, K%64==0; B must have >= n0+128
// valid rows (pad B if N not multiple of 128).
// Epilogues: 0 = plain store to C (bf16 or fp32)
//            1 = x_proj split: col<128 -> aux bf16 (ld 128); col in [128,160)
//                -> aux2 fp32 (ld 32); else dropped
//            2 = delta = softplus(acc + bias[col]) -> C bf16
// ---------------------------------------------------------------------------
__device__ __forceinline__ void async_cp16(const bf16* g, bf16* l) {
    __builtin_amdgcn_global_load_lds(
        (const __attribute__((address_space(1))) void*)g,
        (__attribute__((address_space(3))) void*)l, 16, 0, 0);
}

template <int EPI, typename TC>
__global__ __launch_bounds__(256) void gemm_mfma_nt(
    const bf16* __restrict__ A, const bf16* __restrict__ B,
    TC* __restrict__ C, int M, int N, int K, int lda, int ldb, int ldc,
    const float* __restrict__ bias, bf16* __restrict__ aux,
    float* __restrict__ aux2)
{
    __shared__ bf16 As[128][64];   // 16 KB
    __shared__ bf16 Bs[128][64];   // 16 KB

    const int tid  = threadIdx.x;
    const int lane = tid & 63;
    const int wave = tid >> 6;          // 0..3
    const int wm   = (wave >> 1) * 64;
    const int wn   = (wave & 1) * 64;

    const int m0 = blockIdx.x * 128;
    const int n0 = blockIdx.y * 128;

    f32x4 acc[4][4] = {};

    // staging: one inst = 64 lanes x 16 B = 8 rows x 128 B
    const int srow = lane >> 3;
    const int scol = (lane & 7) * 8;

    for (int k0 = 0; k0 < K; k0 += 64) {
        __syncthreads();
#pragma unroll
        for (int i = 0; i < 4; ++i) {
            int seg = wave * 4 + i;
            int row = seg * 8 + srow;
            async_cp16(A + (size_t)(m0 + row) * lda + k0 + scol, &As[seg * 8][0]);
            async_cp16(B + (size_t)(n0 + row) * ldb + k0 + scol, &Bs[seg * 8][0]);
        }
        __syncthreads();

#pragma unroll
        for (int kk = 0; kk < 64; kk += 32) {
            short8 a[4], b[4];
            const int fr = lane & 15;
            const int fk = kk + (lane >> 4) * 8;
#pragma unroll
            for (int i = 0; i < 4; ++i) {
                a[i] = *(const short8*)&As[wm + i * 16 + fr][fk];
                b[i] = *(const short8*)&Bs[wn + i * 16 + fr][fk];
            }
#pragma unroll
            for (int i = 0; i < 4; ++i)
#pragma unroll
                for (int j = 0; j < 4; ++j)
                    acc[i][j] = __builtin_amdgcn_mfma_f32_16x16x32_bf16(
                        a[i], b[j], acc[i][j], 0, 0, 0);
        }
    }

    // C/D: col = lane&15, row = (lane>>4)*4 + reg   [m89-verified]
#pragma unroll
    for (int i = 0; i < 4; ++i) {
        int row = m0 + wm + i * 16 + (lane >> 4) * 4;
#pragma unroll
        for (int j = 0; j < 4; ++j) {
            int col = n0 + wn + j * 16 + (lane & 15);
#pragma unroll
            for (int r = 0; r < 4; ++r) {
                float v = acc[i][j][r];
                if (EPI == 0) {
                    st1(C + (size_t)(row + r) * ldc + col, v);
                } else if (EPI == 1) {
                    if (col < DT_RANK)
                        aux[(size_t)(row + r) * DT_RANK + col] = f2bf(v);
                    else if (col < DT_RANK + 2 * D_STATE)
                        aux2[(size_t)(row + r) * (2 * D_STATE) + (col - DT_RANK)] = v;
                } else {  // EPI == 2: softplus(acc + bias)
                    float x  = v + bias[col];
                    float sp = fmaxf(x, 0.f) + __logf(1.f + __expf(-fabsf(x)));
                    ((bf16*)C)[(size_t)(row + r) * ldc + col] = f2bf(sp);
                }
            }
        }
    }
}

// ---------------------------------------------------------------------------
// fp32 -> bf16 conversion (4 elems/thread); n must be a multiple of 1024.
// ---------------------------------------------------------------------------
__global__ void cvt_f32_bf16(const float* __restrict__ src,
                             bf16* __restrict__ dst, int n)
{
    int i = (blockIdx.x * blockDim.x + threadIdx.x) * 4;
    if (i >= n) return;
    float4 v = *(const float4*)(src + i);
    bf16 o[4] = { f2bf(v.x), f2bf(v.y), f2bf(v.z), f2bf(v.w) };
    *(ushort4*)(dst + i) = *(ushort4*)o;
}

// W_x (160 x 4096 fp32) -> zero-padded 256 x 4096 bf16
__global__ void cvt_pad_wx(const float* __restrict__ src, bf16* __restrict__ dst)
{
    int i = (blockIdx.x * blockDim.x + threadIdx.x) * 4;   // over 256*4096
    if (i >= 256 * D_INNER) return;
    int row = i / D_INNER;
    bf16 o[4] = {};
    if (row < DT_RANK + 2 * D_STATE) {
        float4 v = *(const float4*)(src + i);
        o[0] = f2bf(v.x); o[1] = f2bf(v.y); o[2] = f2bf(v.z); o[3] = f2bf(v.w);
    }
    *(ushort4*)(dst + i) = *(ushort4*)o;
}

// in-place silu on bf16 buffer (4 elems/thread)
__global__ void silu_inplace(bf16* __restrict__ p, int n)
{
    int i = (blockIdx.x * blockDim.x + threadIdx.x) * 4;
    if (i >= n) return;
    ushort4 v = *(ushort4*)(p + i);
    bf16 o[4];
    const unsigned short* s = (const unsigned short*)&v;
#pragma unroll
    for (int q = 0; q < 4; ++q) {
        float z = __uint_as_float((unsigned)s[q] << 16);
        o[q] = f2bf(z * fast_rcp(1.f + __expf(-z)));
    }
    *(ushort4*)(p + i) = *(ushort4*)o;
}

// ---------------------------------------------------------------------------
// Depthwise causal conv1d (width 4) + bias + SiLU.  bf16 in/out, fp32 math.
// ---------------------------------------------------------------------------
__global__ void conv_silu(const bf16* __restrict__ X,
                          const float* __restrict__ conv_w,
                          const float* __restrict__ conv_b,
                          bf16* __restrict__ xact)
{
    unsigned idx = blockIdx.x * blockDim.x + threadIdx.x;
    if (idx >= (unsigned)BL * D_INNER) return;
    int c = idx & (D_INNER - 1);
    unsigned bl = idx >> 12;
    int l = bl & (SEQLEN - 1);
    int b = bl >> 11;

    float acc = conv_b[c];
#pragma unroll
    for (int t = 0; t < D_CONV; ++t) {
        int ll = l - (D_CONV - 1) + t;
        if (ll >= 0)
            acc = fmaf(bf2f(X[((size_t)b * SEQLEN + ll) * D_INNER + c]),
                       conv_w[c * D_CONV + t], acc);
    }
    xact[(size_t)bl * D_INNER + c] = f2bf(acc * fast_rcp(1.f + __expf(-acc)));
}

// ---------------------------------------------------------------------------
// Selective scan, 8 lanes per channel, 2 states per lane.
// Block 256 = 4 waves = 32 channels; grid (D_INNER/32, BATCH) = 2048 waves.
// All transcendentals except exp(delta*A) hoisted out (delta precomputed via
// dt_proj epilogue; g = silu(z) precomputed in place).  1-step register
// prefetch keeps loads off the fmac recurrence critical path.
// YG holds g on entry, y on exit (per-element read-before-write, same lane).
// ---------------------------------------------------------------------------
__global__ __launch_bounds__(256) void scan_kernel(
    const bf16* __restrict__ U,      // xact (BL, D_INNER)
    const bf16* __restrict__ DLT,    // delta (BL, D_INNER)
    const float* __restrict__ BC,    // (BL, 32): B[16] then C[16]
    const float* __restrict__ A_log,
    const float* __restrict__ Dp,
    bf16* __restrict__ YG)           // in: silu(z); out: y
{
    const int b    = blockIdx.y;
    const int lane = threadIdx.x & 63;
    const int wave = threadIdx.x >> 6;
    const int sub  = lane & 7;          // state pair {2sub, 2sub+1}
    const int grp  = lane >> 3;         // channel within wave
    const int d    = blockIdx.x * 32 + wave * 8 + grp;

    const float2 al = *(const float2*)&A_log[(size_t)d * D_STATE + 2 * sub];
    const float A0 = -__expf(al.x), A1 = -__expf(al.y);
    const float Dv = Dp[d];

    float h0 = 0.f, h1 = 0.f;
    const size_t base = (size_t)b * SEQLEN;

    const bf16*  up  = U   + base * D_INNER + d;
    const bf16*  dlp = DLT + base * D_INNER + d;
    bf16*        ygp = YG  + base * D_INNER + d;
    const float* bcp = BC  + base * (2 * D_STATE) + 2 * sub;

    // prefetch step 0
    float u_n  = bf2f(up[0]);
    float dl_n = bf2f(dlp[0]);
    float g_n  = bf2f(ygp[0]);
    float2 B_n = *(const float2*)(bcp);
    float2 C_n = *(const float2*)(bcp + D_STATE);

    for (int l = 0; l < SEQLEN; ++l) {
        float u = u_n, dl = dl_n, g = g_n;
        float2 Bv = B_n, Cv = C_n;
        if (l + 1 < SEQLEN) {
            size_t off = (size_t)(l + 1) * D_INNER;
            u_n  = bf2f(up[off]);
            dl_n = bf2f(dlp[off]);
            g_n  = bf2f(ygp[off]);
            const float* q = bcp + (size_t)(l + 1) * (2 * D_STATE);
            B_n = *(const float2*)q;
            C_n = *(const float2*)(q + D_STATE);
        }
        float e0 = __expf(dl * A0);
        float e1 = __expf(dl * A1);
        float du = dl * u;
        h0 = fmaf(h0, e0, du * Bv.x);
        h1 = fmaf(h1, e1, du * Bv.y);
        float p = fmaf(h1, Cv.y, h0 * Cv.x);
        p += __shfl_xor(p, 1, 8);
        p += __shfl_xor(p, 2, 8);
        p += __shfl_xor(p, 4, 8);
        if (sub == 0)
            ygp[(size_t)l * D_INNER] = f2bf((p + Dv * u) * g);
    }
}

// ---------------------------------------------------------------------------
// Workspace (total exactly 139,460,608 B — proven safe in R3/R4):
//   buf1  [  0,  64Mi) bf16 : X -> delta -> W_out_bf16
//   buf2  [64Mi, 128Mi) bf16 : Z -> g=silu(z) -> y (in place)
//   tail  [128Mi, +5MiB):  BCbuf fp32 (1 MiB) | dtlr bf16 (2 MiB) |
//                          wxp bf16 (2 MiB; W_dt bf16 reuses it in phase 4)
// d_out doubles as scratch: hs_bf16 (32 MiB) + W_in_bf16 (32 MiB) during
// in_proj; then xact bf16 (64 MiB) until out_proj writes the final fp32.
// ---------------------------------------------------------------------------
extern "C" void kernel_launch(void* const* d_in, const int* in_sizes, int n_in,
                              void* d_out, int out_size, void* d_ws, size_t ws_size,
                              hipStream_t stream)
{
    const float* hs      = (const float*)d_in[0];
    const float* W_in    = (const float*)d_in[1];
    const float* conv_w  = (const float*)d_in[2];
    const float* conv_b  = (const float*)d_in[3];
    const float* W_x     = (const float*)d_in[4];
    const float* W_dt    = (const float*)d_in[5];
    const float* dt_bias = (const float*)d_in[6];
    const float* A_log   = (const float*)d_in[7];
    const float* Dp      = (const float*)d_in[8];
    const float* W_out   = (const float*)d_in[9];
    float* out = (float*)d_out;

    const size_t nBig = (size_t)BL * D_INNER;            // 33,554,432
    const size_t need = 2 * nBig * sizeof(bf16)
                      + (size_t)BL * 160 * sizeof(float);
    if (ws_size < need) {
        hipMemsetAsync(d_out, 0, (size_t)out_size * sizeof(float), stream);
        return;
    }

    bf16*  buf1  = (bf16*)d_ws;                          // 64 MiB
    bf16*  buf2  = buf1 + nBig;                          // 64 MiB
    float* BCbuf = (float*)(buf2 + nBig);                // 1 MiB (BL x 32 fp32)
    bf16*  dtlr  = (bf16*)(BCbuf + (size_t)BL * 2 * D_STATE); // 2 MiB
    bf16*  wxp   = dtlr + (size_t)BL * DT_RANK;          // 2 MiB
    bf16*  wdtb  = wxp;                                  // reuse (phase 4)

    const int nHS = BL * D_MODEL;                        // 16,777,216
    const int nWI = 2 * D_INNER * D_MODEL;               // 16,777,216 (full W_in)
    const int nWH = D_INNER * D_MODEL;                   // 8,388,608
    bf16* hsb  = (bf16*)d_out;                           // 32 MiB
    bf16* wb   = hsb + nHS;                              // 32 MiB (full W_in bf16)
    bf16* xact = (bf16*)d_out;                           // after hsb/wb die

    // --- Phase 1: in_proj (bf16 MFMA) ------------------------------------
    cvt_f32_bf16<<<nHS / 1024, 256, 0, stream>>>(hs, hsb, nHS);
    cvt_f32_bf16<<<nWI / 1024, 256, 0, stream>>>(W_in, wb, nWI);
    // Z = hs @ W_in[4096:]^T -> buf2
    gemm_mfma_nt<0, bf16><<<dim3(BL / 128, D_INNER / 128), 256, 0, stream>>>(
        hsb, wb + (size_t)nWH, buf2, BL, D_INNER, D_MODEL,
        D_MODEL, D_MODEL, D_INNER, nullptr, nullptr, nullptr);
    // X = hs @ W_in[:4096]^T -> buf1
    gemm_mfma_nt<0, bf16><<<dim3(BL / 128, D_INNER / 128), 256, 0, stream>>>(
        hsb, wb, buf1, BL, D_INNER, D_MODEL,
        D_MODEL, D_MODEL, D_INNER, nullptr, nullptr, nullptr);

    // --- Phase 2: conv + SiLU -> xact (d_out; hsb/wb dead) ---------------
    conv_silu<<<(BL * D_INNER + 255) / 256, 256, 0, stream>>>(
        buf1, conv_w, conv_b, xact);

    // --- Phase 3: x_proj (MFMA, padded N=256) -> dtlr bf16 + BCbuf fp32 --
    cvt_pad_wx<<<(256 * D_INNER) / 1024, 256, 0, stream>>>(W_x, wxp);
    gemm_mfma_nt<1, float><<<dim3(BL / 128, 2), 256, 0, stream>>>(
        xact, wxp, (float*)nullptr, BL, 256, D_INNER,
        D_INNER, D_INNER, 0, nullptr, dtlr, BCbuf);

    // --- Phase 4: dt_proj (MFMA) + fused softplus(+bias) -> delta (buf1) -
    cvt_f32_bf16<<<(D_INNER * DT_RANK) / 1024, 256, 0, stream>>>(W_dt, wdtb,
                                                                 D_INNER * DT_RANK);
    gemm_mfma_nt<2, bf16><<<dim3(BL / 128, D_INNER / 128), 256, 0, stream>>>(
        dtlr, wdtb, buf1, BL, D_INNER, DT_RANK,
        DT_RANK, DT_RANK, D_INNER, dt_bias, nullptr, nullptr);

    // --- Phase 4.5: g = silu(z) in place on buf2 -------------------------
    silu_inplace<<<(int)(nBig / 1024), 256, 0, stream>>>(buf2, (int)nBig);

    // --- Phase 5: scan -> y in buf2 --------------------------------------
    scan_kernel<<<dim3(D_INNER / 32, BATCH), 256, 0, stream>>>(
        xact, buf1, BCbuf, A_log, Dp, buf2);

    // --- Phase 6: out_proj (MFMA).  W_out -> buf1 (delta dead) -----------
    cvt_f32_bf16<<<nWH / 1024, 256, 0, stream>>>(W_out, buf1, nWH);
    gemm_mfma_nt<0, float><<<dim3(BL / 128, D_MODEL / 128), 256, 0, stream>>>(
        buf2, buf1, out, BL, D_MODEL, D_INNER,
        D_INNER, D_INNER, D_MODEL, nullptr, nullptr, nullptr);
}

// Round 6
// 1619.619 us; speedup vs baseline: 5.0826x; 1.3385x over previous
//
#include <hip/hip_runtime.h>
#include <hip/hip_bf16.h>
#include <math.h>

// Problem constants
#define D_MODEL 2048
#define D_STATE 16
#define D_CONV  4
#define DT_RANK 128
#define D_INNER 4096
#define BATCH   4
#define SEQLEN  2048
#define BL      (BATCH * SEQLEN)   // 8192 tokens

typedef __hip_bfloat16 bf16;
typedef __attribute__((ext_vector_type(8))) short  short8;   // 8 bf16 (4 VGPRs)
typedef __attribute__((ext_vector_type(4))) float  f32x4;

__device__ __forceinline__ float bf2f(bf16 v) { return __bfloat162float(v); }
__device__ __forceinline__ bf16  f2bf(float v) { return __float2bfloat16(v); }
__device__ __forceinline__ float us2f(unsigned short v) {
    return __uint_as_float((unsigned)v << 16);
}
__device__ __forceinline__ void st1(float* p, float v) { *p = v; }
__device__ __forceinline__ void st1(bf16* p, float v)  { *p = f2bf(v); }
__device__ __forceinline__ float fast_rcp(float x) { return __builtin_amdgcn_rcpf(x); }

__device__ __forceinline__ void async_cp16(const void* g, void* l) {
    __builtin_amdgcn_global_load_lds(
        (const __attribute__((address_space(1))) void*)g,
        (__attribute__((address_space(3))) void*)l, 16, 0, 0);
}

// ---------------------------------------------------------------------------
// bf16 MFMA NT GEMM: C[M,N] = sum_k A[m,k]*B[n,k].
// 128x128 tile, BK=64, 256 threads (4 waves 2x2), 4x4 16x16x32 frags/wave.
// Epilogues: 0 = plain store; 1 = x_proj split (dt_lr bf16 / BC fp32);
//            2 = softplus(acc + bias[col]) -> bf16
// ---------------------------------------------------------------------------
template <int EPI, typename TC>
__global__ __launch_bounds__(256) void gemm_mfma_nt(
    const bf16* __restrict__ A, const bf16* __restrict__ B,
    TC* __restrict__ C, int M, int N, int K, int lda, int ldb, int ldc,
    const float* __restrict__ bias, bf16* __restrict__ aux,
    float* __restrict__ aux2)
{
    __shared__ bf16 As[128][64];   // 16 KB
    __shared__ bf16 Bs[128][64];   // 16 KB

    const int tid  = threadIdx.x;
    const int lane = tid & 63;
    const int wave = tid >> 6;          // 0..3
    const int wm   = (wave >> 1) * 64;
    const int wn   = (wave & 1) * 64;

    const int m0 = blockIdx.x * 128;
    const int n0 = blockIdx.y * 128;

    f32x4 acc[4][4] = {};

    const int srow = lane >> 3;
    const int scol = (lane & 7) * 8;

    for (int k0 = 0; k0 < K; k0 += 64) {
        __syncthreads();
#pragma unroll
        for (int i = 0; i < 4; ++i) {
            int seg = wave * 4 + i;
            int row = seg * 8 + srow;
            async_cp16(A + (size_t)(m0 + row) * lda + k0 + scol, &As[seg * 8][0]);
            async_cp16(B + (size_t)(n0 + row) * ldb + k0 + scol, &Bs[seg * 8][0]);
        }
        __syncthreads();

#pragma unroll
        for (int kk = 0; kk < 64; kk += 32) {
            short8 a[4], b[4];
            const int fr = lane & 15;
            const int fk = kk + (lane >> 4) * 8;
#pragma unroll
            for (int i = 0; i < 4; ++i) {
                a[i] = *(const short8*)&As[wm + i * 16 + fr][fk];
                b[i] = *(const short8*)&Bs[wn + i * 16 + fr][fk];
            }
#pragma unroll
            for (int i = 0; i < 4; ++i)
#pragma unroll
                for (int j = 0; j < 4; ++j)
                    acc[i][j] = __builtin_amdgcn_mfma_f32_16x16x32_bf16(
                        a[i], b[j], acc[i][j], 0, 0, 0);
        }
    }

    // C/D: col = lane&15, row = (lane>>4)*4 + reg   [m89-verified]
#pragma unroll
    for (int i = 0; i < 4; ++i) {
        int row = m0 + wm + i * 16 + (lane >> 4) * 4;
#pragma unroll
        for (int j = 0; j < 4; ++j) {
            int col = n0 + wn + j * 16 + (lane & 15);
#pragma unroll
            for (int r = 0; r < 4; ++r) {
                float v = acc[i][j][r];
                if (EPI == 0) {
                    st1(C + (size_t)(row + r) * ldc + col, v);
                } else if (EPI == 1) {
                    if (col < DT_RANK)
                        aux[(size_t)(row + r) * DT_RANK + col] = f2bf(v);
                    else if (col < DT_RANK + 2 * D_STATE)
                        aux2[(size_t)(row + r) * (2 * D_STATE) + (col - DT_RANK)] = v;
                } else {  // EPI == 2: softplus(acc + bias)
                    float x  = v + bias[col];
                    float sp = fmaxf(x, 0.f) + __logf(1.f + __expf(-fabsf(x)));
                    ((bf16*)C)[(size_t)(row + r) * ldc + col] = f2bf(sp);
                }
            }
        }
    }
}

// ---------------------------------------------------------------------------
// fp32 -> bf16 conversion (4 elems/thread); n must be a multiple of 1024.
// ---------------------------------------------------------------------------
__global__ void cvt_f32_bf16(const float* __restrict__ src,
                             bf16* __restrict__ dst, int n)
{
    int i = (blockIdx.x * blockDim.x + threadIdx.x) * 4;
    if (i >= n) return;
    float4 v = *(const float4*)(src + i);
    bf16 o[4] = { f2bf(v.x), f2bf(v.y), f2bf(v.z), f2bf(v.w) };
    *(ushort4*)(dst + i) = *(ushort4*)o;
}

// W_x (160 x 4096 fp32) -> zero-padded 256 x 4096 bf16
__global__ void cvt_pad_wx(const float* __restrict__ src, bf16* __restrict__ dst)
{
    int i = (blockIdx.x * blockDim.x + threadIdx.x) * 4;
    if (i >= 256 * D_INNER) return;
    int row = i / D_INNER;
    bf16 o[4] = {};
    if (row < DT_RANK + 2 * D_STATE) {
        float4 v = *(const float4*)(src + i);
        o[0] = f2bf(v.x); o[1] = f2bf(v.y); o[2] = f2bf(v.z); o[3] = f2bf(v.w);
    }
    *(ushort4*)(dst + i) = *(ushort4*)o;
}

// ---------------------------------------------------------------------------
// Depthwise causal conv1d (width 4) + bias + SiLU.  bf16 in/out, fp32 math.
// ---------------------------------------------------------------------------
__global__ void conv_silu(const bf16* __restrict__ X,
                          const float* __restrict__ conv_w,
                          const float* __restrict__ conv_b,
                          bf16* __restrict__ xact)
{
    unsigned idx = blockIdx.x * blockDim.x + threadIdx.x;
    if (idx >= (unsigned)BL * D_INNER) return;
    int c = idx & (D_INNER - 1);
    unsigned bl = idx >> 12;
    int l = bl & (SEQLEN - 1);
    int b = bl >> 11;

    float acc = conv_b[c];
#pragma unroll
    for (int t = 0; t < D_CONV; ++t) {
        int ll = l - (D_CONV - 1) + t;
        if (ll >= 0)
            acc = fmaf(bf2f(X[((size_t)b * SEQLEN + ll) * D_INNER + c]),
                       conv_w[c * D_CONV + t], acc);
    }
    xact[(size_t)bl * D_INNER + c] = f2bf(acc * fast_rcp(1.f + __expf(-acc)));
}

// ---------------------------------------------------------------------------
// Selective scan, LDS-tile double-buffered.
// Block = 256 thr (4 waves) owns 32 channels; tiles of 64 steps staged via
// global_load_lds (u/delta/z bf16, BC fp32), next tile streams during compute.
// 8 lanes per channel x 2 states per lane; y-reduce via 3-step shfl_xor.
// silu(z) fused (sub==0 lane).  Z and Y may alias (tile t stores vs t+1
// fetches touch disjoint rows).
// LDS: 2*(3*4KB + 8KB) = 40 KB -> 4 blocks/CU.
// ---------------------------------------------------------------------------
#define SCH 64   // steps per tile

__global__ __launch_bounds__(256) void scan_kernel(
    const bf16* __restrict__ U,      // xact   (BL, D_INNER)
    const bf16* __restrict__ DLT,    // delta  (BL, D_INNER)
    const bf16* __restrict__ Z,      // z      (BL, D_INNER)
    const float* __restrict__ BC,    // (BL, 32): B[16] then C[16]
    const float* __restrict__ A_log,
    const float* __restrict__ Dp,
    bf16* __restrict__ Y)            // output y (may alias Z)
{
    __shared__ unsigned short Us[2][SCH][32];
    __shared__ unsigned short Ds[2][SCH][32];
    __shared__ unsigned short Zs[2][SCH][32];
    __shared__ float         BCs[2][SCH][32];

    const int b    = blockIdx.y;
    const int d0   = blockIdx.x * 32;
    const int lane = threadIdx.x & 63;
    const int wave = threadIdx.x >> 6;
    const int sub  = lane & 7;          // state pair {2sub, 2sub+1}
    const int grp  = lane >> 3;         // channel within wave
    const int ci   = wave * 8 + grp;    // channel within block (0..31)
    const int d    = d0 + ci;

    const float2 al = *(const float2*)&A_log[(size_t)d * D_STATE + 2 * sub];
    const float A0 = -__expf(al.x), A1 = -__expf(al.y);
    const float Dv = Dp[d];

    const size_t base = (size_t)b * SEQLEN;

    // staging geometry
    const int r16 = lane >> 2;          // 0..15 (row within 16-row segment)
    const int c8  = (lane & 3) * 8;     // channel offset for bf16 tiles
    const int r8  = lane >> 3;          // 0..7  (row within 8-row segment)
    const int c4  = (lane & 7) * 4;     // float offset for BC tile

    auto stage = [&](int bb, int l0) {
        {   // bf16 tiles: 1 instr/wave each (16 rows x 64 B)
            int row = wave * 16 + r16;
            size_t g = (base + l0 + row) * (size_t)D_INNER + d0 + c8;
            async_cp16(U   + g, &Us[bb][wave * 16][0]);
            async_cp16(DLT + g, &Ds[bb][wave * 16][0]);
            async_cp16(Z   + g, &Zs[bb][wave * 16][0]);
        }
#pragma unroll
        for (int j = 0; j < 2; ++j) {   // BC tile: 2 instr/wave (8 rows x 128 B)
            int row = wave * 16 + j * 8 + r8;
            const float* g = BC + (base + l0 + row) * (2 * D_STATE) + c4;
            async_cp16(g, &BCs[bb][wave * 16 + j * 8][0]);
        }
    };

    float h0 = 0.f, h1 = 0.f;

    stage(0, 0);
    __syncthreads();   // drains vmcnt: tile 0 resident

    for (int t = 0; t < SEQLEN / SCH; ++t) {
        const int cur = t & 1, nxt = cur ^ 1;
        if (t + 1 < SEQLEN / SCH) stage(nxt, (t + 1) * SCH);

        for (int l = 0; l < SCH; ++l) {
            float u  = us2f(Us[cur][l][ci]);
            float dl = us2f(Ds[cur][l][ci]);
            float e0 = __expf(dl * A0);
            float e1 = __expf(dl * A1);
            float du = dl * u;
            float B0 = BCs[cur][l][2 * sub];
            float B1 = BCs[cur][l][2 * sub + 1];
            float C0 = BCs[cur][l][D_STATE + 2 * sub];
            float C1 = BCs[cur][l][D_STATE + 2 * sub + 1];
            h0 = fmaf(h0, e0, du * B0);
            h1 = fmaf(h1, e1, du * B1);
            float p = fmaf(h1, C1, h0 * C0);
            p += __shfl_xor(p, 1, 8);
            p += __shfl_xor(p, 2, 8);
            p += __shfl_xor(p, 4, 8);
            if (sub == 0) {
                float z = us2f(Zs[cur][l][ci]);
                float g = z * fast_rcp(1.f + __expf(-z));
                Y[(base + t * SCH + l) * (size_t)D_INNER + d] =
                    f2bf((p + Dv * u) * g);
            }
        }
        __syncthreads();   // all waves done with cur; nxt stage drained
    }
}

// ---------------------------------------------------------------------------
// Workspace (total exactly 139,460,608 B — proven safe):
//   buf1  [  0,  64Mi) bf16 : X -> delta -> W_out_bf16
//   buf2  [64Mi, 128Mi) bf16 : Z -> y (in place, via scan)
//   tail  [128Mi, +5MiB): BCbuf fp32 (1 MiB) | dtlr bf16 (2 MiB) |
//                         wxp bf16 (2 MiB; W_dt bf16 reuses it)
// d_out doubles as scratch: hs_bf16 (32 MiB) + W_in_bf16 (32 MiB) during
// in_proj; then xact bf16 (64 MiB) until out_proj writes the final fp32.
// ---------------------------------------------------------------------------
extern "C" void kernel_launch(void* const* d_in, const int* in_sizes, int n_in,
                              void* d_out, int out_size, void* d_ws, size_t ws_size,
                              hipStream_t stream)
{
    const float* hs      = (const float*)d_in[0];
    const float* W_in    = (const float*)d_in[1];
    const float* conv_w  = (const float*)d_in[2];
    const float* conv_b  = (const float*)d_in[3];
    const float* W_x     = (const float*)d_in[4];
    const float* W_dt    = (const float*)d_in[5];
    const float* dt_bias = (const float*)d_in[6];
    const float* A_log   = (const float*)d_in[7];
    const float* Dp      = (const float*)d_in[8];
    const float* W_out   = (const float*)d_in[9];
    float* out = (float*)d_out;

    const size_t nBig = (size_t)BL * D_INNER;            // 33,554,432
    const size_t need = 2 * nBig * sizeof(bf16)
                      + (size_t)BL * 160 * sizeof(float);
    if (ws_size < need) {
        hipMemsetAsync(d_out, 0, (size_t)out_size * sizeof(float), stream);
        return;
    }

    bf16*  buf1  = (bf16*)d_ws;                          // 64 MiB
    bf16*  buf2  = buf1 + nBig;                          // 64 MiB
    float* BCbuf = (float*)(buf2 + nBig);                // 1 MiB (BL x 32 fp32)
    bf16*  dtlr  = (bf16*)(BCbuf + (size_t)BL * 2 * D_STATE); // 2 MiB
    bf16*  wxp   = dtlr + (size_t)BL * DT_RANK;          // 2 MiB
    bf16*  wdtb  = wxp;                                  // reuse (phase 4)

    const int nHS = BL * D_MODEL;                        // 16,777,216
    const int nWI = 2 * D_INNER * D_MODEL;               // 16,777,216
    const int nWH = D_INNER * D_MODEL;                   // 8,388,608
    bf16* hsb  = (bf16*)d_out;                           // 32 MiB
    bf16* wb   = hsb + nHS;                              // 32 MiB
    bf16* xact = (bf16*)d_out;                           // after hsb/wb die

    // --- Phase 1: in_proj (bf16 MFMA) ------------------------------------
    cvt_f32_bf16<<<nHS / 1024, 256, 0, stream>>>(hs, hsb, nHS);
    cvt_f32_bf16<<<nWI / 1024, 256, 0, stream>>>(W_in, wb, nWI);
    gemm_mfma_nt<0, bf16><<<dim3(BL / 128, D_INNER / 128), 256, 0, stream>>>(
        hsb, wb + (size_t)nWH, buf2, BL, D_INNER, D_MODEL,
        D_MODEL, D_MODEL, D_INNER, nullptr, nullptr, nullptr);
    gemm_mfma_nt<0, bf16><<<dim3(BL / 128, D_INNER / 128), 256, 0, stream>>>(
        hsb, wb, buf1, BL, D_INNER, D_MODEL,
        D_MODEL, D_MODEL, D_INNER, nullptr, nullptr, nullptr);

    // --- Phase 2: conv + SiLU -> xact (d_out; hsb/wb dead) ---------------
    conv_silu<<<(BL * D_INNER + 255) / 256, 256, 0, stream>>>(
        buf1, conv_w, conv_b, xact);

    // --- Phase 3: x_proj (MFMA, padded N=256) -> dtlr bf16 + BCbuf fp32 --
    cvt_pad_wx<<<(256 * D_INNER) / 1024, 256, 0, stream>>>(W_x, wxp);
    gemm_mfma_nt<1, float><<<dim3(BL / 128, 2), 256, 0, stream>>>(
        xact, wxp, (float*)nullptr, BL, 256, D_INNER,
        D_INNER, D_INNER, 0, nullptr, dtlr, BCbuf);

    // --- Phase 4: dt_proj (MFMA) + fused softplus(+bias) -> delta (buf1) -
    cvt_f32_bf16<<<(D_INNER * DT_RANK) / 1024, 256, 0, stream>>>(W_dt, wdtb,
                                                                 D_INNER * DT_RANK);
    gemm_mfma_nt<2, bf16><<<dim3(BL / 128, D_INNER / 128), 256, 0, stream>>>(
        dtlr, wdtb, buf1, BL, D_INNER, DT_RANK,
        DT_RANK, DT_RANK, D_INNER, dt_bias, nullptr, nullptr);

    // --- Phase 5: scan (silu(z) fused) -> y in buf2 ----------------------
    scan_kernel<<<dim3(D_INNER / 32, BATCH), 256, 0, stream>>>(
        xact, buf1, buf2, BCbuf, A_log, Dp, buf2);

    // --- Phase 6: out_proj (MFMA).  W_out -> buf1 (delta dead) -----------
    cvt_f32_bf16<<<nWH / 1024, 256, 0, stream>>>(W_out, buf1, nWH);
    gemm_mfma_nt<0, float><<<dim3(BL / 128, D_MODEL / 128), 256, 0, stream>>>(
        buf2, buf1, out, BL, D_MODEL, D_INNER,
        D_INNER, D_INNER, D_MODEL, nullptr, nullptr, nullptr);
}